// Round 2
// baseline (1636.361 us; speedup 1.0000x reference)
//
#include <hip/hip_runtime.h>

// MPLayer rewrite v2: binned gather (no f32 atomics) + fully-fused per-node
// compute with register-resident weight columns (no LDS weight reads).
//
//   z = deg>0 ? relu((sum_e [node_x[src]|edge_x]) @ W_pre + deg*b_pre) : z_init
//   h = relu(concat(node_x, z) @ W_upd + b_upd)

#define N_NODES 100000
#define N_EDGES 1600000
#define ND 32
#define ED 32
#define OD 32
#define ZD 64   // ND+ED
#define CAP 64  // per-node edge-slot capacity; Poisson(16) max-deg ~40 << 64

// K_fill: one thread per edge. cursor[] becomes deg[] as a side effect.
__global__ __launch_bounds__(256) void fill_bins(
    const int* __restrict__ dst, int* __restrict__ cursor, int* __restrict__ bins)
{
    int e = blockIdx.x * 256 + threadIdx.x;
    if (e >= N_EDGES) return;
    int d = dst[e];
    int pos = atomicAdd(&cursor[d], 1);
    if (pos < CAP) bins[d * CAP + pos] = e;
}

// K_fused: one wave per node (persistent, grid-stride by wave).
// Lane c holds W_pre[:,c] (64 VGPRs) and W_upd[:,c&31] (96 VGPRs).
// Cross-lane operands via __shfl (v_readlane -> SGPR fma operand).
__global__ __launch_bounds__(256, 2) void fused_node(
    const float* __restrict__ node_x, const float* __restrict__ edge_x,
    const float* __restrict__ z_init,
    const float* __restrict__ W_pre, const float* __restrict__ b_pre,
    const float* __restrict__ W_upd, const float* __restrict__ b_upd,
    const int* __restrict__ src,
    const int* __restrict__ deg, const int* __restrict__ bins,
    float* __restrict__ out)
{
    const int l = threadIdx.x & 63;
    const int c = l & 31;

    // Weight columns into registers (coalesced: lanes read consecutive floats).
    float Wp[ZD];
    #pragma unroll
    for (int k = 0; k < ZD; ++k) Wp[k] = W_pre[k * ZD + l];
    float Wu[ND + ZD];  // 96
    #pragma unroll
    for (int k = 0; k < ND + ZD; ++k) Wu[k] = W_upd[k * OD + c];
    const float bp = b_pre[l];
    const float bu = b_upd[c];

    int gwave = (blockIdx.x * 256 + threadIdx.x) >> 6;
    int nwaves = (gridDim.x * 256) >> 6;

    for (int n = gwave; n < N_NODES; n += nwaves) {
        int dg = deg[n];           // wave-uniform
        float z;
        if (dg > 0) {
            int dgc = (dg < CAP) ? dg : CAP;
            // Lane l holds edge id / src id for slot l of this node's bin row.
            int bv = (l < dgc) ? bins[n * CAP + l] : 0;
            int sv = (l < dgc) ? src[bv] : 0;
            // Accumulate raw concat features: lane<32 -> node_x col, else edge_x col.
            float acc = 0.0f;
            int i = 0;
            for (; i + 1 < dgc; i += 2) {   // unroll-2 for memory-level parallelism
                int e0 = __shfl(bv, i),     e1 = __shfl(bv, i + 1);
                int s0 = __shfl(sv, i),     s1 = __shfl(sv, i + 1);
                float v0 = (l < ND) ? node_x[(long)s0 * ND + l]
                                    : edge_x[(long)e0 * ED + (l - ND)];
                float v1 = (l < ND) ? node_x[(long)s1 * ND + l]
                                    : edge_x[(long)e1 * ED + (l - ND)];
                acc += v0;
                acc += v1;
            }
            if (i < dgc) {
                int e0 = __shfl(bv, i);
                int s0 = __shfl(sv, i);
                acc += (l < ND) ? node_x[(long)s0 * ND + l]
                                : edge_x[(long)e0 * ED + (l - ND)];
            }
            // z_c = relu( sum_k acc_k * W_pre[k][c] + deg * b_pre[c] )
            float zz = (float)dg * bp;
            #pragma unroll
            for (int k = 0; k < ZD; ++k)
                zz += __shfl(acc, k) * Wp[k];
            z = fmaxf(zz, 0.0f);
        } else {
            z = z_init[(long)n * ZD + l];   // no relu on the z_init path
        }

        // h_c = relu( sum_{k<32} x_k Wu[k][c] + sum_{k<64} z_k Wu[32+k][c] + bu )
        // All 64 lanes compute (upper half redundant) to keep shfl sources uniform.
        float xv = node_x[(long)n * ND + c];   // lane k<32 holds x_k
        float part = bu;
        #pragma unroll
        for (int k = 0; k < ND; ++k)
            part += __shfl(xv, k) * Wu[k];
        #pragma unroll
        for (int k = 0; k < ZD; ++k)
            part += __shfl(z, k) * Wu[ND + k];
        if (l < OD)
            out[(long)n * OD + l] = fmaxf(part, 0.0f);
    }
}

extern "C" void kernel_launch(void* const* d_in, const int* in_sizes, int n_in,
                              void* d_out, int out_size, void* d_ws, size_t ws_size,
                              hipStream_t stream)
{
    const float* node_x = (const float*)d_in[0];
    const float* edge_x = (const float*)d_in[1];
    const float* z_init = (const float*)d_in[2];
    const float* W_pre  = (const float*)d_in[3];
    const float* b_pre  = (const float*)d_in[4];
    const float* W_upd  = (const float*)d_in[5];
    const float* b_upd  = (const float*)d_in[6];
    const int*   src    = (const int*)d_in[7];
    const int*   dst    = (const int*)d_in[8];
    float* out = (float*)d_out;

    // ws: cursor/deg [N] ints, then bins [N*CAP] ints  (~26 MB total)
    int* cursor = (int*)d_ws;
    int* bins   = cursor + N_NODES;

    hipMemsetAsync(cursor, 0, N_NODES * sizeof(int), stream);

    fill_bins<<<(N_EDGES + 255) / 256, 256, 0, stream>>>(dst, cursor, bins);

    fused_node<<<1024, 256, 0, stream>>>(node_x, edge_x, z_init,
                                         W_pre, b_pre, W_upd, b_upd,
                                         src, cursor, bins, out);
}

// Round 4
// 1097.513 us; speedup vs baseline: 1.4910x; 1.4910x over previous
//
#include <hip/hip_runtime.h>

// MPLayer v4: counting-sort buckets + LDS-resident segment sum (ds_add_f32,
// no global f32 atomics) + register-weight matvecs via v_readlane broadcasts.
//
//   S[d] = sum_{e:dst=d} concat(node_x[src[e]], edge_x[e])   (LDS accumulate)
//   z    = deg>0 ? relu(S @ W_pre + deg*b_pre) : z_init      (K2 epilogue)
//   h    = relu(concat(node_x, z) @ W_upd + b_upd)           (K3)

#define N_NODES 100000
#define N_EDGES 1600000
#define ND 32
#define ED 32
#define OD 32
#define ZD 64     // ND+ED
#define NPB 240   // nodes per bucket: S slice = 240*64*4 = 61440 B LDS
#define NBLK 417  // ceil(100000/240)
#define NSUB 32   // sub-buckets per bucket (spreads counter contention)
#define SCAP 240  // entries per sub-bucket; mean 120, sigma 11 -> +11 sigma
// region per bucket: NSUB*SCAP int2 = 7680*8 B = 61440 B == S slice (aliased)
#define REG_I2 7680
#define REG_F32 15360
#define EMASK ((1 << 21) - 1)

__device__ inline float bcast(float v, int lane) {
    // v_readlane_b32 -> SGPR operand of v_fmac. No LDS traffic.
    return __uint_as_float(__builtin_amdgcn_readlane(__float_as_uint(v), lane));
}

// K1: counting-sort fill. Entry = (e | dloc<<21, src[e]).
__global__ __launch_bounds__(256) void bucket_fill(
    const int* __restrict__ src, const int* __restrict__ dst,
    int* __restrict__ cnt, int2* __restrict__ buf)
{
    int e = blockIdx.x * 256 + threadIdx.x;
    if (e >= N_EDGES) return;
    int d = dst[e];
    int b = d / NPB;               // magic-mul div by constant
    int dloc = d - b * NPB;
    int sub = e & (NSUB - 1);
    int pos = atomicAdd(&cnt[b * NSUB + sub], 1);
    if (pos < SCAP)
        buf[(long)b * REG_I2 + sub * SCAP + pos] = make_int2(e | (dloc << 21), src[e]);
}

// K2: one block per bucket. Accumulate concat-features into LDS with
// ds_add_f32 (1 instr per edge, 2-way bank alias = free), then compute z
// with W_pre columns in VGPRs and write z in-place over the bucket region.
__global__ __launch_bounds__(1024, 4) void aggregate_z(
    const float* __restrict__ node_x, const float* __restrict__ edge_x,
    const float* __restrict__ z_init,
    const float* __restrict__ W_pre, const float* __restrict__ b_pre,
    const int* __restrict__ cnt, int2* __restrict__ buf)
{
    __shared__ float S[NPB * ZD];    // 61440 B
    __shared__ float degS[NPB];      //  960 B
    const int b = blockIdx.x;
    const int w = threadIdx.x >> 6;
    const int l = threadIdx.x & 63;

    for (int i = threadIdx.x; i < NPB * ZD; i += 1024) S[i] = 0.0f;
    for (int i = threadIdx.x; i < NPB; i += 1024) degS[i] = 0.0f;
    __syncthreads();

    const int2* region = buf + (long)b * REG_I2;

    // 16 waves x 2 sub-buckets each
    for (int j = w; j < NSUB; j += 16) {
        int c = cnt[b * NSUB + j];
        if (c > SCAP) c = SCAP;
        const int2* sb = region + j * SCAP;

        int base = 0;
        for (; base + 8 <= c; base += 8) {          // hot path: full groups
            int2 E = sb[base + (l & 7)];            // lane jj holds entry jj
            if (l < 8) atomicAdd(&degS[E.x >> 21], 1.0f);
            float vals[8]; int dls[8];
            #pragma unroll
            for (int jj = 0; jj < 8; ++jj) {
                int pk = __shfl(E.x, jj);
                int s  = __shfl(E.y, jj);
                dls[jj] = pk >> 21;
                int e   = pk & EMASK;
                const float* p = (l < ND) ? (node_x + (long)s * ND + l)
                                          : (edge_x + (long)e * ED + (l - ND));
                vals[jj] = *p;                       // 8 independent loads in flight
            }
            #pragma unroll
            for (int jj = 0; jj < 8; ++jj)
                atomicAdd(&S[dls[jj] * ZD + l], vals[jj]);   // ds_add_f32
        }
        for (; base < c; ++base) {                  // tail, one at a time
            int2 E = sb[base];                      // same-address broadcast load
            int dloc = E.x >> 21;
            int e    = E.x & EMASK;
            const float* p = (l < ND) ? (node_x + (long)E.y * ND + l)
                                      : (edge_x + (long)e * ED + (l - ND));
            float v = *p;
            atomicAdd(&S[dloc * ZD + l], v);
            if (l == 0) atomicAdd(&degS[dloc], 1.0f);
        }
    }
    __syncthreads();

    // Epilogue: z = deg>0 ? relu(S@W_pre + deg*b_pre) : z_init.
    // W_pre column l in 64 VGPRs per lane; S row broadcast via readlane.
    float Wp[ZD];
    #pragma unroll
    for (int k = 0; k < ZD; ++k) Wp[k] = W_pre[k * ZD + l];
    const float bp = b_pre[l];

    float* zg = (float*)region;     // overwrite dead bucket region with z
    for (int nloc = w; nloc < NPB; nloc += 16) {
        int n = b * NPB + nloc;
        float sv = S[nloc * ZD + l];
        float dg = degS[nloc];
        float a0 = dg * bp, a1 = 0.0f;
        #pragma unroll
        for (int k = 0; k < ZD; k += 2) {
            a0 += bcast(sv, k)     * Wp[k];
            a1 += bcast(sv, k + 1) * Wp[k + 1];
        }
        float z;
        if (dg > 0.0f) z = fmaxf(a0 + a1, 0.0f);
        else           z = (n < N_NODES) ? z_init[(long)n * ZD + l] : 0.0f;
        zg[nloc * ZD + l] = z;
    }
}

// K3: h = relu(concat(node_x, z) @ W_upd + b_upd). One wave per node,
// grid-stride; W_upd column (96 floats) in VGPRs, broadcasts via readlane.
__global__ __launch_bounds__(256, 2) void h_update(
    const float* __restrict__ node_x,
    const float* __restrict__ W_upd, const float* __restrict__ b_upd,
    const float* __restrict__ zbuf, float* __restrict__ out)
{
    const int l = threadIdx.x & 63;
    const int c = l & 31;

    float Wu[ND + ZD];   // 96
    #pragma unroll
    for (int k = 0; k < ND + ZD; ++k) Wu[k] = W_upd[k * OD + c];
    const float bu = b_upd[c];

    int gw = (blockIdx.x * 256 + threadIdx.x) >> 6;
    int nw = gridDim.x * 4;

    for (int n = gw; n < N_NODES; n += nw) {
        int b = n / NPB;
        int nloc = n - b * NPB;
        float zv = zbuf[(long)b * REG_F32 + nloc * ZD + l];   // lane l: z_l
        float xv = node_x[(long)n * ND + c];                  // lane k<32: x_k
        float h0 = bu, h1 = 0.0f;
        #pragma unroll
        for (int k = 0; k < ND; k += 2) {
            h0 += bcast(xv, k)     * Wu[k];
            h1 += bcast(xv, k + 1) * Wu[k + 1];
        }
        #pragma unroll
        for (int k = 0; k < ZD; k += 2) {
            h0 += bcast(zv, k)     * Wu[ND + k];
            h1 += bcast(zv, k + 1) * Wu[ND + k + 1];
        }
        if (l < OD)
            out[(long)n * OD + l] = fmaxf(h0 + h1, 0.0f);
    }
}

extern "C" void kernel_launch(void* const* d_in, const int* in_sizes, int n_in,
                              void* d_out, int out_size, void* d_ws, size_t ws_size,
                              hipStream_t stream)
{
    const float* node_x = (const float*)d_in[0];
    const float* edge_x = (const float*)d_in[1];
    const float* z_init = (const float*)d_in[2];
    const float* W_pre  = (const float*)d_in[3];
    const float* b_pre  = (const float*)d_in[4];
    const float* W_upd  = (const float*)d_in[5];
    const float* b_upd  = (const float*)d_in[6];
    const int*   src    = (const int*)d_in[7];
    const int*   dst    = (const int*)d_in[8];
    float* out = (float*)d_out;

    // ws: buf [NBLK * REG_I2] int2 (25.62 MB), then cnt [NBLK*NSUB] int (53 KB)
    int2* buf = (int2*)d_ws;
    int*  cnt = (int*)(buf + (size_t)NBLK * REG_I2);

    (void)hipMemsetAsync(cnt, 0, (size_t)NBLK * NSUB * sizeof(int), stream);

    bucket_fill<<<(N_EDGES + 255) / 256, 256, 0, stream>>>(src, dst, cnt, buf);

    aggregate_z<<<NBLK, 1024, 0, stream>>>(node_x, edge_x, z_init,
                                           W_pre, b_pre, cnt, buf);

    h_update<<<1024, 256, 0, stream>>>(node_x, W_upd, b_upd,
                                       (const float*)buf, out);
}

// Round 5
// 800.104 us; speedup vs baseline: 2.0452x; 1.3717x over previous
//
#include <hip/hip_runtime.h>

// MPLayer v5: exact CSR permutation so every large access is sequential.
//   deg  = histogram(dst)                       (int atomics)
//   cursor = exclusive_scan(deg)                (3-kernel parallel scan)
//   rows[slot] = edge_x[e]; sidx[slot] = src[e] (seq read, full-line write)
//   z_csr: per-node contiguous reduce + W_pre matvec (readlane weights)
//   h_upd: W_upd matvec (readlane weights)
// Fallback (ws too small): R1 atomic scatter + same epilogues (~500us).

#define N_NODES 100000
#define N_EDGES 1600000
#define ND 32
#define ED 32
#define OD 32
#define ZD 64
#define NTILE 98   // ceil(N_NODES/1024)

__device__ inline float bcast(float v, int lane) {
    return __uint_as_float(__builtin_amdgcn_readlane(__float_as_uint(v), lane));
}

// ---------- CSR build ----------
__global__ __launch_bounds__(256) void hist(const int* __restrict__ dst,
                                            int* __restrict__ cnt) {
    int e = blockIdx.x * 256 + threadIdx.x;
    if (e < N_EDGES) atomicAdd(&cnt[dst[e]], 1);
}

__global__ __launch_bounds__(1024) void scan_part(const int* __restrict__ cnt,
                                                  int* __restrict__ part) {
    __shared__ int s[1024];
    int i = blockIdx.x * 1024 + threadIdx.x;
    s[threadIdx.x] = (i < N_NODES) ? cnt[i] : 0;
    __syncthreads();
    for (int off = 512; off > 0; off >>= 1) {
        if (threadIdx.x < off) s[threadIdx.x] += s[threadIdx.x + off];
        __syncthreads();
    }
    if (threadIdx.x == 0) part[blockIdx.x] = s[0];
}

__global__ void scan_top(int* part) {   // 1 block, 128 threads, NTILE<=128
    __shared__ int s[128];
    int v = (threadIdx.x < NTILE) ? part[threadIdx.x] : 0;
    s[threadIdx.x] = v;
    __syncthreads();
    for (int off = 1; off < 128; off <<= 1) {
        int u = (threadIdx.x >= off) ? s[threadIdx.x - off] : 0;
        __syncthreads();
        s[threadIdx.x] += u;
        __syncthreads();
    }
    if (threadIdx.x < NTILE) part[threadIdx.x] = s[threadIdx.x] - v;  // exclusive
}

__global__ __launch_bounds__(1024) void scan_local(const int* __restrict__ cnt,
                                                   const int* __restrict__ part,
                                                   int* __restrict__ cursor) {
    __shared__ int s[1024];
    int i = blockIdx.x * 1024 + threadIdx.x;
    int v = (i < N_NODES) ? cnt[i] : 0;
    s[threadIdx.x] = v;
    __syncthreads();
    for (int off = 1; off < 1024; off <<= 1) {
        int u = (threadIdx.x >= off) ? s[threadIdx.x - off] : 0;
        __syncthreads();
        s[threadIdx.x] += u;
        __syncthreads();
    }
    if (i < N_NODES) cursor[i] = part[blockIdx.x] + s[threadIdx.x] - v;
}

// ---------- permute: half-wave (32 lanes) per edge ----------
__global__ __launch_bounds__(256) void permute(
    const float* __restrict__ edge_x, const int* __restrict__ src,
    const int* __restrict__ dst, int* __restrict__ cursor,
    float* __restrict__ rows, int* __restrict__ sidx)
{
    long t = (long)blockIdx.x * 256 + threadIdx.x;
    int e = (int)(t >> 5);
    int p = (int)(t & 31);
    int l = threadIdx.x & 63;
    if (e >= N_EDGES) return;
    int pos = 0;
    if (p == 0) pos = atomicAdd(&cursor[dst[e]], 1);
    pos = __shfl(pos, l & 32);              // lanes 0-31 <- lane0, 32-63 <- lane32
    float v = edge_x[(long)e * ED + p];     // sequential 128B per half-wave
    rows[(long)pos * ED + p] = v;           // full aligned 128B line store
    if (p == 0) sidx[pos] = src[e];
}

// ---------- fused aggregate + z (CSR path) ----------
__global__ __launch_bounds__(256, 1) void z_csr(
    const float* __restrict__ node_x, const float* __restrict__ z_init,
    const float* __restrict__ W_pre, const float* __restrict__ b_pre,
    const int* __restrict__ cnt, const int* __restrict__ cursor,  // cursor = end
    const float* __restrict__ rows, const int* __restrict__ sidx,
    float* __restrict__ zbuf)
{
    const int l = threadIdx.x & 63;
    float Wp[ZD];
    #pragma unroll
    for (int k = 0; k < ZD; ++k) Wp[k] = W_pre[k * ZD + l];
    const float bp = b_pre[l];

    int w  = (blockIdx.x * 256 + threadIdx.x) >> 6;
    int nw = (gridDim.x * 256) >> 6;
    for (int n = w; n < N_NODES; n += nw) {
        int dg = cnt[n];
        float z;
        if (dg > 0) {
            int end = cursor[n];
            int j = end - dg;
            float acc = 0.0f;
            for (; j + 4 <= end; j += 4) {          // 4 lines in flight
                int s0 = sidx[j], s1 = sidx[j+1], s2 = sidx[j+2], s3 = sidx[j+3];
                float v0 = (l < ND) ? node_x[(long)s0 * ND + l] : rows[(long)j     * ED + (l-ND)];
                float v1 = (l < ND) ? node_x[(long)s1 * ND + l] : rows[(long)(j+1) * ED + (l-ND)];
                float v2 = (l < ND) ? node_x[(long)s2 * ND + l] : rows[(long)(j+2) * ED + (l-ND)];
                float v3 = (l < ND) ? node_x[(long)s3 * ND + l] : rows[(long)(j+3) * ED + (l-ND)];
                acc += v0 + v1 + v2 + v3;
            }
            for (; j < end; ++j) {
                int s0 = sidx[j];
                acc += (l < ND) ? node_x[(long)s0 * ND + l] : rows[(long)j * ED + (l-ND)];
            }
            float a0 = (float)dg * bp, a1 = 0.0f;
            #pragma unroll
            for (int k = 0; k < ZD; k += 2) {
                a0 += bcast(acc, k)     * Wp[k];
                a1 += bcast(acc, k + 1) * Wp[k + 1];
            }
            z = fmaxf(a0 + a1, 0.0f);
        } else {
            z = z_init[(long)n * ZD + l];
        }
        zbuf[(long)n * ZD + l] = z;
    }
}

// ---------- fallback: R1 atomic scatter + dense z ----------
__global__ __launch_bounds__(256) void edge_scatter(
    const float* __restrict__ node_x, const float* __restrict__ edge_x,
    const int* __restrict__ src, const int* __restrict__ dst,
    float* __restrict__ S, int* __restrict__ degI)
{
    long t = (long)blockIdx.x * 256 + threadIdx.x;
    int e = (int)(t >> 6), l = (int)(t & 63);
    if (e >= N_EDGES) return;
    int s = src[e], d = dst[e];
    float v = (l < ND) ? node_x[(long)s * ND + l] : edge_x[(long)e * ED + (l - ND)];
    atomicAdd(&S[(long)d * ZD + l], v);
    if (l == 0) atomicAdd(&degI[d], 1);
}

__global__ __launch_bounds__(256, 1) void z_dense(
    const float* __restrict__ z_init,
    const float* __restrict__ W_pre, const float* __restrict__ b_pre,
    float* __restrict__ S, const int* __restrict__ degI)
{
    const int l = threadIdx.x & 63;
    float Wp[ZD];
    #pragma unroll
    for (int k = 0; k < ZD; ++k) Wp[k] = W_pre[k * ZD + l];
    const float bp = b_pre[l];
    int w  = (blockIdx.x * 256 + threadIdx.x) >> 6;
    int nw = (gridDim.x * 256) >> 6;
    for (int n = w; n < N_NODES; n += nw) {
        int dg = degI[n];
        float sv = S[(long)n * ZD + l];
        float z;
        if (dg > 0) {
            float a0 = (float)dg * bp, a1 = 0.0f;
            #pragma unroll
            for (int k = 0; k < ZD; k += 2) {
                a0 += bcast(sv, k)     * Wp[k];
                a1 += bcast(sv, k + 1) * Wp[k + 1];
            }
            z = fmaxf(a0 + a1, 0.0f);
        } else {
            z = z_init[(long)n * ZD + l];
        }
        S[(long)n * ZD + l] = z;   // in-place: wave owns row
    }
}

// ---------- shared h update ----------
__global__ __launch_bounds__(256, 1) void h_upd(
    const float* __restrict__ node_x,
    const float* __restrict__ W_upd, const float* __restrict__ b_upd,
    const float* __restrict__ zbuf, float* __restrict__ out)
{
    const int l = threadIdx.x & 63;
    const int c = l & 31;
    float Wu[ND + ZD];   // 96
    #pragma unroll
    for (int k = 0; k < ND + ZD; ++k) Wu[k] = W_upd[k * OD + c];
    const float bu = b_upd[c];
    int w  = (blockIdx.x * 256 + threadIdx.x) >> 6;
    int nw = (gridDim.x * 256) >> 6;
    for (int n = w; n < N_NODES; n += nw) {
        float zv = zbuf[(long)n * ZD + l];
        float xv = node_x[(long)n * ND + c];
        float h0 = bu, h1 = 0.0f;
        #pragma unroll
        for (int k = 0; k < ND; k += 2) {
            h0 += bcast(xv, k)     * Wu[k];
            h1 += bcast(xv, k + 1) * Wu[k + 1];
        }
        #pragma unroll
        for (int k = 0; k < ZD; k += 2) {
            h0 += bcast(zv, k)     * Wu[ND + k];
            h1 += bcast(zv, k + 1) * Wu[ND + k + 1];
        }
        if (l < OD) out[(long)n * OD + l] = fmaxf(h0 + h1, 0.0f);
    }
}

extern "C" void kernel_launch(void* const* d_in, const int* in_sizes, int n_in,
                              void* d_out, int out_size, void* d_ws, size_t ws_size,
                              hipStream_t stream)
{
    const float* node_x = (const float*)d_in[0];
    const float* edge_x = (const float*)d_in[1];
    const float* z_init = (const float*)d_in[2];
    const float* W_pre  = (const float*)d_in[3];
    const float* b_pre  = (const float*)d_in[4];
    const float* W_upd  = (const float*)d_in[5];
    const float* b_upd  = (const float*)d_in[6];
    const int*   src    = (const int*)d_in[7];
    const int*   dst    = (const int*)d_in[8];
    float* out = (float*)d_out;

    // CSR-path ws layout: rows[E*32]f | zbuf[N*64]f | sidx[E]i | cnt[N]i |
    //                     part[128]i | cursor[N]i   (~238 MB)
    size_t need = ((size_t)N_EDGES * ED + (size_t)N_NODES * ZD) * 4
                + ((size_t)N_EDGES + 2 * (size_t)N_NODES + 128) * 4;

    if (ws_size >= need) {
        float* rows   = (float*)d_ws;
        float* zbuf   = rows + (size_t)N_EDGES * ED;
        int*   sidx   = (int*)(zbuf + (size_t)N_NODES * ZD);
        int*   cnt    = sidx + N_EDGES;
        int*   part   = cnt + N_NODES;
        int*   cursor = part + 128;

        (void)hipMemsetAsync(cnt, 0, N_NODES * sizeof(int), stream);
        hist<<<(N_EDGES + 255) / 256, 256, 0, stream>>>(dst, cnt);
        scan_part<<<NTILE, 1024, 0, stream>>>(cnt, part);
        scan_top<<<1, 128, 0, stream>>>(part);
        scan_local<<<NTILE, 1024, 0, stream>>>(cnt, part, cursor);
        permute<<<(int)(((long)N_EDGES * 32 + 255) / 256), 256, 0, stream>>>(
            edge_x, src, dst, cursor, rows, sidx);
        z_csr<<<2048, 256, 0, stream>>>(node_x, z_init, W_pre, b_pre,
                                        cnt, cursor, rows, sidx, zbuf);
        h_upd<<<2048, 256, 0, stream>>>(node_x, W_upd, b_upd, zbuf, out);
    } else {
        // Fallback (~26 MB): S[N*64]f | degI[N]i
        float* S    = (float*)d_ws;
        int*   degI = (int*)(S + (size_t)N_NODES * ZD);
        (void)hipMemsetAsync(d_ws, 0,
            ((size_t)N_NODES * ZD + N_NODES) * sizeof(float), stream);
        edge_scatter<<<(int)(((long)N_EDGES * 64 + 255) / 256), 256, 0, stream>>>(
            node_x, edge_x, src, dst, S, degI);
        z_dense<<<2048, 256, 0, stream>>>(z_init, W_pre, b_pre, S, degI);
        h_upd<<<2048, 256, 0, stream>>>(node_x, W_upd, b_upd, S, out);
    }
}